// Round 8
// baseline (21.552 us; speedup 1.0000x reference)
//
#include <hip/hip_runtime.h>
#include <math.h>
#include <stdint.h>

#define HF 64
#define WF 64
#define CC 512
#define NROI 256
#define NBINS 21   // 1 + 4 + 16

__device__ __forceinline__ float4 max4(float4 a, float4 b) {
    float4 r;
    r.x = fmaxf(a.x, b.x); r.y = fmaxf(a.y, b.y);
    r.z = fmaxf(a.z, b.z); r.w = fmaxf(a.w, b.w);
    return r;
}

__device__ __forceinline__ float4 ld4(const float* __restrict__ img, uint32_t byteoff) {
    return *(const float4*)((const char*)img + byteoff);
}

// Fused kernel v3: block = (roi, channel-quarter of 128 ch), 512 threads = 8 waves.
//   wave wv: jy = wv>>1 (y fine-strip), rp = wv&1 (row parity within strip).
//   Each wave processes ALL 4 jx bins of its rows: jx fully unrolled -> 4
//   INDEPENDENT acc chains (true MLP-4), cols clamped to bin last column
//   (duplicates exact for max; <= +20% traffic). All 8 waves do near-identical
//   work (skew <= 1 row) -> negligible __syncthreads wait.
//   lanes: cl = lane&31 -> 4 channels (float4), half = lane>>5 -> col parity.
// p4 = rp-pair combine (LDS); p2/p1 hierarchical (LDS). All max-combines exact;
// boundary arithmetic bitwise-identical to reference (rintf, __fmul_rn/__fadd_rn).
// XCD swizzle (proven r2-r7): bid&7 -> XCD, quarter q=(bid&7)>>1 -> XCD pair {2q,2q+1};
// per-XCD image slice 2 MB < 4 MiB L2.
__global__ __launch_bounds__(512, 8) void roi_pool_fused(
    const float* __restrict__ img,
    const float* __restrict__ rois,
    float* __restrict__ out)
{
    __shared__ float ldsA[4][2][4][128];   // [jy][rp][jx][ch]  16 KB
    __shared__ float ldsB[4][4][128];      // [jy][jx][ch]       8 KB
    __shared__ float ldsC[2][2][128];      // [i2][j2][ch]       2 KB

    const int bid  = blockIdx.x;                    // [0, 1024)
    const int q    = (bid & 7) >> 1;                // channel quarter
    const int roi  = ((bid >> 3) << 1) | (bid & 1); // [0, 256) bijective
    const int tid  = threadIdx.x;
    const int wv   = tid >> 6;                      // 0..7
    const int jy   = wv >> 1;                       // y fine-strip
    const int rp   = wv & 1;                        // row parity
    const int lane = tid & 63;
    const int half = lane >> 5;                     // col parity
    const int cl   = lane & 31;                     // channel lane
    const int c0   = q * 128 + cl * 4;

    const float x = rois[roi * 4 + 0];
    const float y = rois[roi * 4 + 1];
    const float w = rois[roi * 4 + 2];
    const float h = rois[roi * 4 + 3];

    // Reference quirk: x-boundaries (W axis) use col_len = h/p; y-boundaries use w/p.
    const float clh = h * 0.25f;   // exact
    const float clw = w * 0.25f;   // exact

    int bx[5];
#pragma unroll
    for (int i = 0; i < 5; ++i)
        bx[i] = (int)rintf(__fadd_rn(x, __fmul_rn((float)i, clh)));

    const int y1 = (int)rintf(__fadd_rn(y, __fmul_rn((float)jy,       clw)));
    const int y2 = (int)rintf(__fadd_rn(y, __fmul_rn((float)(jy + 1), clw)));

    // widest bin -> shared col-iteration count (clamped duplicates for narrower bins)
    const int w01 = max(bx[1] - bx[0], bx[2] - bx[1]);
    const int w23 = max(bx[3] - bx[2], bx[4] - bx[3]);
    const int K   = (max(w01, w23) + 1) >> 1;

    float4 acc[4];
#pragma unroll
    for (int jx = 0; jx < 4; ++jx) {
        acc[jx].x = -INFINITY; acc[jx].y = -INFINITY;
        acc[jx].z = -INFINITY; acc[jx].w = -INFINITY;
    }

    const uint32_t ROWB = WF * CC * 4;   // 131072
    const uint32_t PXB  = CC * 4;        // 2048
    const uint32_t cb   = (uint32_t)c0 * 4;

    for (int r = y1 + rp; r < y2; r += 2) {
        const uint32_t ro = cb + (uint32_t)r * ROWB;
        for (int k = 0; k < K; ++k) {
            const int cc2 = 2 * k + half;
#pragma unroll
            for (int jx = 0; jx < 4; ++jx) {
                const int col = min(bx[jx] + cc2, bx[jx + 1] - 1);
                acc[jx] = max4(acc[jx], ld4(img, ro + (uint32_t)col * PXB));
            }
        }
    }

    // combine col-parity halves (same channels, disjoint-or-duplicate pixel sets)
#pragma unroll
    for (int jx = 0; jx < 4; ++jx) {
        float4 a = acc[jx];
        a.x = fmaxf(a.x, __shfl_xor(a.x, 32));
        a.y = fmaxf(a.y, __shfl_xor(a.y, 32));
        a.z = fmaxf(a.z, __shfl_xor(a.z, 32));
        a.w = fmaxf(a.w, __shfl_xor(a.w, 32));
        acc[jx] = a;
    }

    if (half == 0) {
#pragma unroll
        for (int jx = 0; jx < 4; ++jx)
            *(float4*)(&ldsA[jy][rp][jx][cl * 4]) = acc[jx];
    }
    __syncthreads();

    float* outr = out + (size_t)roi * (NBINS * CC) + c0;

    // p4: row-parity combine, write global + stash (waves with rp==0)
    if (rp == 0 && half == 0) {
#pragma unroll
        for (int jx = 0; jx < 4; ++jx) {
            const float4 m = max4(*(const float4*)(&ldsA[jy][0][jx][cl * 4]),
                                  *(const float4*)(&ldsA[jy][1][jx][cl * 4]));
            *(float4*)(outr + (size_t)(5 + jx * 4 + jy) * CC) = m;
            *(float4*)(&ldsB[jy][jx][cl * 4]) = m;
        }
    }
    __syncthreads();

    // p2: waves 0..3 -> coarse bin (i2 = wv>>1, j2 = wv&1)
    if (wv < 4 && half == 0) {
        const int i2 = wv >> 1;
        const int j2 = wv & 1;
        const float4 f00 = *(const float4*)(&ldsB[2*j2  ][2*i2  ][cl * 4]);
        const float4 f01 = *(const float4*)(&ldsB[2*j2  ][2*i2+1][cl * 4]);
        const float4 f10 = *(const float4*)(&ldsB[2*j2+1][2*i2  ][cl * 4]);
        const float4 f11 = *(const float4*)(&ldsB[2*j2+1][2*i2+1][cl * 4]);
        const float4 a = max4(max4(f00, f01), max4(f10, f11));
        *(float4*)(outr + (size_t)(1 + i2 * 2 + j2) * CC) = a;
        *(float4*)(&ldsC[i2][j2][cl * 4]) = a;
    }
    __syncthreads();

    // p1: wave 0
    if (wv == 0 && half == 0) {
        const float4 a00 = *(const float4*)(&ldsC[0][0][cl * 4]);
        const float4 a01 = *(const float4*)(&ldsC[0][1][cl * 4]);
        const float4 a10 = *(const float4*)(&ldsC[1][0][cl * 4]);
        const float4 a11 = *(const float4*)(&ldsC[1][1][cl * 4]);
        *(float4*)(outr) = max4(max4(a00, a01), max4(a10, a11));
    }
}

extern "C" void kernel_launch(void* const* d_in, const int* in_sizes, int n_in,
                              void* d_out, int out_size, void* d_ws, size_t ws_size,
                              hipStream_t stream) {
    const float* img  = (const float*)d_in[0];   // (1,64,64,512) fp32
    const float* rois = (const float*)d_in[1];   // (1,256,4) fp32
    float* out = (float*)d_out;                  // (1,256,21*512) fp32

    dim3 grid(NROI * 4);     // (roi, quarter) = 1024 blocks
    dim3 block(512);         // 8 waves = 4 jy-strips x 2 row-parities
    roi_pool_fused<<<grid, block, 0, stream>>>(img, rois, out);
}